// Round 19
// baseline (112.381 us; speedup 1.0000x reference)
//
#include <hip/hip_runtime.h>

typedef __attribute__((ext_vector_type(4))) short short4v;
typedef __attribute__((ext_vector_type(8))) short short8v;
typedef __attribute__((ext_vector_type(4))) float float4v;
typedef __attribute__((ext_vector_type(4))) int int4v;

#define GLD_LDS16(gsrc, ldst)                                                             \
    __builtin_amdgcn_global_load_lds(                                                     \
        (const __attribute__((address_space(1))) void*)(gsrc),                            \
        (__attribute__((address_space(3))) void*)(ldst), 16, 0, 0)

__device__ __forceinline__ short f2bf(float f) {
    unsigned u = __builtin_bit_cast(unsigned, f);
    u += 0x7fffu + ((u >> 16) & 1u);
    return (short)(u >> 16);
}

// ---------------- fused prep: x cvt (blocks 0..4095) + W transpose (4096..8191) ----
__global__ void k_prep(const float* __restrict__ x, short* __restrict__ xb,
                       const float* __restrict__ W0, const float* __restrict__ W1,
                       const float* __restrict__ W2, const float* __restrict__ W3,
                       short* __restrict__ Wt) {
    __shared__ float tile[32][33];
    int bid = blockIdx.x;
    if (bid < 4096) {
        int i = bid * 256 + threadIdx.x;
        float4v v = ((const float4v*)x)[i];
        short4v o;
        o[0] = f2bf(v[0]); o[1] = f2bf(v[1]); o[2] = f2bf(v[2]); o[3] = f2bf(v[3]);
        ((short4v*)xb)[i] = o;
        return;
    }
    int L = bid - 4096;                  // 0..4095
    int z = L >> 10;                     // weight 0..3
    int xy = L & 1023;
    int bx = xy & 31, by = xy >> 5;
    const float* W = z == 0 ? W0 : z == 1 ? W1 : z == 2 ? W2 : W3;
    short* dst = Wt + (size_t)z * 1024 * 1024;
    int x0 = bx * 32, y0 = by * 32;
    int tx = threadIdx.x & 31, ty = threadIdx.x >> 5;   // 32 x 8
#pragma unroll
    for (int j = 0; j < 4; j++) {
        int r = ty + j * 8;
        tile[r][tx] = W[(size_t)(y0 + r) * 1024 + x0 + tx];
    }
    __syncthreads();
#pragma unroll
    for (int j = 0; j < 4; j++) {
        int r = ty + j * 8;
        dst[(size_t)(x0 + r) * 1024 + y0 + tx] = f2bf(tile[tx][r]);
    }
}

// ---------------- QKV GEMM v3: 128x128 tile, 4 waves, 64x64/wave (m97 shape) --------
// grid (32, 24): which = nfull>>10 (block-uniform). which<2 -> Q/K head-major;
// which==2 -> V via swapped MFMA operands -> V^T [B,H,Dh,S].
__launch_bounds__(256, 2)
__global__ void k_gemmQKV(const short* __restrict__ A, const short* __restrict__ Wtb,
                          short* __restrict__ Qb, short* __restrict__ Kb,
                          short* __restrict__ Vtb) {
    __shared__ short As[2][128][64];
    __shared__ short Bs[2][128][64];
    int t = threadIdx.x;
    int l = t & 63, w = t >> 6;          // 4 waves
    int wm = w >> 1, wn = w & 1;         // 2x2 quadrants; wave owns 64x64
    int lr = l & 15, lg = l >> 4;
    int m0 = blockIdx.x * 128;
    int nfull = blockIdx.y * 128;
    int which = nfull >> 10;
    int nb = nfull & 1023;

    // staging: thread t covers 16B slot s = t + i*256 (i=0..3) of each 16KB half
    int srow = t >> 3;                   // 0..31 (+32i)
    int cs = (((t & 7) ^ (srow & 7)) * 8);
    const short* Ag[4];
    const short* Bg[4];
    int ldof[4];
#pragma unroll
    for (int i = 0; i < 4; i++) {
        int row = srow + i * 32;
        Ag[i] = A + (size_t)(m0 + row) * 1024 + cs;
        Bg[i] = Wtb + (size_t)(nfull + row) * 1024 + cs;
        ldof[i] = (t + i * 256) * 8;
    }

    float4v acc[4][4] = {};

#define STAGE(bb, k0)                                                         \
    do {                                                                      \
        _Pragma("unroll")                                                     \
        for (int i = 0; i < 4; i++) {                                         \
            GLD_LDS16(Ag[i] + (k0), (short*)As[bb] + ldof[i]);                \
            GLD_LDS16(Bg[i] + (k0), (short*)Bs[bb] + ldof[i]);                \
        }                                                                     \
    } while (0)

    STAGE(0, 0);
    __syncthreads();
    int cur = 0;

    for (int kt = 0; kt < 16; kt++) {
        if (kt + 1 < 16) STAGE(cur ^ 1, (kt + 1) * 64);
#pragma unroll
        for (int ks = 0; ks < 2; ks++) {
            short8v af[4], bfv[4];
            int hh = ks * 4 + lg;
#pragma unroll
            for (int fm = 0; fm < 4; fm++) {
                int ra = wm * 64 + fm * 16 + lr;
                af[fm] = *(const short8v*)&As[cur][ra][((hh ^ (ra & 7)) * 8)];
            }
#pragma unroll
            for (int fn = 0; fn < 4; fn++) {
                int rb = wn * 64 + fn * 16 + lr;
                bfv[fn] = *(const short8v*)&Bs[cur][rb][((hh ^ (rb & 7)) * 8)];
            }
            __builtin_amdgcn_s_setprio(1);
            if (which == 2) {
#pragma unroll
                for (int fm = 0; fm < 4; fm++)
#pragma unroll
                    for (int fn = 0; fn < 4; fn++)
                        acc[fm][fn] = __builtin_amdgcn_mfma_f32_16x16x32_bf16(bfv[fn], af[fm], acc[fm][fn], 0, 0, 0);
            } else {
#pragma unroll
                for (int fm = 0; fm < 4; fm++)
#pragma unroll
                    for (int fn = 0; fn < 4; fn++)
                        acc[fm][fn] = __builtin_amdgcn_mfma_f32_16x16x32_bf16(af[fm], bfv[fn], acc[fm][fn], 0, 0, 0);
            }
            __builtin_amdgcn_s_setprio(0);
        }
        __syncthreads();
        cur ^= 1;
    }
#undef STAGE

    if (which < 2) {
        short* out = (which == 0) ? Qb : Kb;
        float scale = (which == 0) ? 0.125f * 1.44269504088896f : 1.0f;
#pragma unroll
        for (int fm = 0; fm < 4; fm++)
#pragma unroll
            for (int fn = 0; fn < 4; fn++)
#pragma unroll
                for (int r = 0; r < 4; r++) {
                    int m = m0 + wm * 64 + fm * 16 + lg * 4 + r;
                    int n = nb + wn * 64 + fn * 16 + lr;
                    float v = acc[fm][fn][r] * scale;
                    int b = m >> 11, s = m & 2047, h = n >> 6, dh = n & 63;
                    out[(((size_t)(b * 16 + h)) * 2048 + s) * 64 + dh] = f2bf(v);
                }
    } else {
#pragma unroll
        for (int fm = 0; fm < 4; fm++)
#pragma unroll
            for (int fn = 0; fn < 4; fn++)
#pragma unroll
                for (int r = 0; r < 4; r++) {
                    int n = nb + wn * 64 + fn * 16 + lg * 4 + r;
                    int m = m0 + wm * 64 + fm * 16 + lr;
                    int b = m >> 11, s = m & 2047, h = n >> 6, dh = n & 63;
                    Vtb[(((size_t)(b * 16 + h)) * 64 + dh) * 2048 + s] = f2bf(acc[fm][fn][r]);
                }
    }
}

// ---------------- O-projection GEMM v3 (fp32 out, m97 shape) ----------------
__launch_bounds__(256, 2)
__global__ void k_gemmO(const short* __restrict__ A, const short* __restrict__ Bt,
                        float* __restrict__ outF) {
    __shared__ short As[2][128][64];
    __shared__ short Bs[2][128][64];
    int t = threadIdx.x;
    int l = t & 63, w = t >> 6;
    int wm = w >> 1, wn = w & 1;
    int lr = l & 15, lg = l >> 4;
    int m0 = blockIdx.x * 128, n0 = blockIdx.y * 128;

    int srow = t >> 3;
    int cs = (((t & 7) ^ (srow & 7)) * 8);
    const short* Ag[4];
    const short* Bg[4];
    int ldof[4];
#pragma unroll
    for (int i = 0; i < 4; i++) {
        int row = srow + i * 32;
        Ag[i] = A + (size_t)(m0 + row) * 1024 + cs;
        Bg[i] = Bt + (size_t)(n0 + row) * 1024 + cs;
        ldof[i] = (t + i * 256) * 8;
    }

    float4v acc[4][4] = {};

#define STAGE(bb, k0)                                                         \
    do {                                                                      \
        _Pragma("unroll")                                                     \
        for (int i = 0; i < 4; i++) {                                         \
            GLD_LDS16(Ag[i] + (k0), (short*)As[bb] + ldof[i]);                \
            GLD_LDS16(Bg[i] + (k0), (short*)Bs[bb] + ldof[i]);                \
        }                                                                     \
    } while (0)

    STAGE(0, 0);
    __syncthreads();
    int cur = 0;

    for (int kt = 0; kt < 16; kt++) {
        if (kt + 1 < 16) STAGE(cur ^ 1, (kt + 1) * 64);
#pragma unroll
        for (int ks = 0; ks < 2; ks++) {
            short8v af[4], bfv[4];
            int hh = ks * 4 + lg;
#pragma unroll
            for (int fm = 0; fm < 4; fm++) {
                int ra = wm * 64 + fm * 16 + lr;
                af[fm] = *(const short8v*)&As[cur][ra][((hh ^ (ra & 7)) * 8)];
            }
#pragma unroll
            for (int fn = 0; fn < 4; fn++) {
                int rb = wn * 64 + fn * 16 + lr;
                bfv[fn] = *(const short8v*)&Bs[cur][rb][((hh ^ (rb & 7)) * 8)];
            }
            __builtin_amdgcn_s_setprio(1);
#pragma unroll
            for (int fm = 0; fm < 4; fm++)
#pragma unroll
                for (int fn = 0; fn < 4; fn++)
                    acc[fm][fn] = __builtin_amdgcn_mfma_f32_16x16x32_bf16(af[fm], bfv[fn], acc[fm][fn], 0, 0, 0);
            __builtin_amdgcn_s_setprio(0);
        }
        __syncthreads();
        cur ^= 1;
    }
#undef STAGE

#pragma unroll
    for (int fm = 0; fm < 4; fm++)
#pragma unroll
        for (int fn = 0; fn < 4; fn++)
#pragma unroll
            for (int r = 0; r < 4; r++) {
                int m = m0 + wm * 64 + fm * 16 + lg * 4 + r;
                int n = n0 + wn * 64 + fn * 16 + lr;
                outF[(size_t)m * 1024 + n] = acc[fm][fn][r];
            }
}

// ---------------- causal flash attention v16 (unchanged from R17) ----------------
__launch_bounds__(256, 2)
__global__ void k_attn(const short* __restrict__ Qb, const short* __restrict__ Kb,
                       const short* __restrict__ Vtb, short* __restrict__ Ob) {
    __shared__ short K_lds[2][64][64];
    __shared__ short V_lds[2][64][64];
    int t = threadIdx.x;
    int l = t & 63, w = t >> 6;
    int lr = l & 15, lg = l >> 4;

    int L = blockIdx.x;                      // 0..511
    int bh = L & 31;                         // L%8 = bh%8 -> XCD affinity
    int g = L >> 5;                          // 0..15
    int p = (g < 8) ? g : 23 - g;            // heavy first; CU pair sums constant
    int nch = 32 - p;                        // staged chunks (covers hi tile)

    const short* Qp = Qb + (size_t)bh * 2048 * 64;
    const short* Kp = Kb + (size_t)bh * 2048 * 64;
    const short* Vp = Vtb + (size_t)bh * 64 * 2048;

    auto stage = [&](int bb, int kv0) {
#pragma unroll
        for (int i = 0; i < 2; i++) {
            int s = t + i * 256;
            int row = s >> 3, cg = s & 7;
            int cs = (cg ^ (row & 7)) * 8;
            GLD_LDS16(&Kp[(size_t)(kv0 + row) * 64 + cs], (short*)K_lds[bb] + (size_t)s * 8);
            GLD_LDS16(&Vp[(size_t)row * 2048 + kv0 + cs], (short*)V_lds[bb] + (size_t)s * 8);
        }
    };

    stage(0, 0);

    int q0a = (31 - p) * 64 + w * 16;        // sub-tile A rows (hi tile)
    int q0b = p * 64 + w * 16;               // sub-tile B rows (lo tile)
    short8v qf0a = *(const short8v*)&Qp[(size_t)(q0a + lr) * 64 + lg * 8];
    short8v qf1a = *(const short8v*)&Qp[(size_t)(q0a + lr) * 64 + 32 + lg * 8];
    short8v qf0b = *(const short8v*)&Qp[(size_t)(q0b + lr) * 64 + lg * 8];
    short8v qf1b = *(const short8v*)&Qp[(size_t)(q0b + lr) * 64 + 32 + lg * 8];

    float4v oa[4] = {}, ob[4] = {};
    float mra = -3e38f, mrb = -3e38f;
    float lsa = 0.f, lsb = 0.f;
    int cur = 0;
    int b = bh >> 4, h = bh & 15;
    int g0 = lg >> 1;
    int hb = (lg & 1) * 4;

    auto softmax_pack = [&](float4v (&s)[4], float& mr, float& ls, float4v (&o)[4],
                            short8v& pa0, short8v& pa1) {
        float mx = -3e38f;
#pragma unroll
        for (int t4 = 0; t4 < 4; t4++)
#pragma unroll
            for (int r = 0; r < 4; r++) mx = fmaxf(mx, s[t4][r]);

        if (!__all(mx - mr <= 8.f)) {
            float m_ = fmaxf(mx, __shfl_xor(mx, 16));
            m_ = fmaxf(m_, __shfl_xor(m_, 32));
            float mnew = fmaxf(mr, m_);
            float sc = __builtin_amdgcn_exp2f(mr - mnew);
            mr = mnew;
            ls *= sc;
#pragma unroll
            for (int r = 0; r < 4; r++) {
                float scq = __shfl(sc, lg * 4 + r);
                o[0][r] *= scq; o[1][r] *= scq; o[2][r] *= scq; o[3][r] *= scq;
            }
        }
        unsigned d[8];
#pragma unroll
        for (int t4 = 0; t4 < 4; t4++) {
            float e0 = __builtin_amdgcn_exp2f(s[t4][0] - mr);
            float e1 = __builtin_amdgcn_exp2f(s[t4][1] - mr);
            float e2 = __builtin_amdgcn_exp2f(s[t4][2] - mr);
            float e3 = __builtin_amdgcn_exp2f(s[t4][3] - mr);
            ls += (e0 + e1) + (e2 + e3);
            asm("v_cvt_pk_bf16_f32 %0, %1, %2" : "=v"(d[2 * t4])     : "v"(e0), "v"(e1));
            asm("v_cvt_pk_bf16_f32 %0, %1, %2" : "=v"(d[2 * t4 + 1]) : "v"(e2), "v"(e3));
        }
        pa0 = __builtin_bit_cast(short8v, int4v{(int)d[0], (int)d[1], (int)d[2], (int)d[3]});
        pa1 = __builtin_bit_cast(short8v, int4v{(int)d[4], (int)d[5], (int)d[6], (int)d[7]});
    };

    __syncthreads();

    for (int ci = 0; ci < nch; ci++) {
        int kv0 = ci * 64;
        bool dual = (ci <= p);

        if (ci + 1 < nch) stage(cur ^ 1, (ci + 1) * 64);

        const short* Kf = (const short*)K_lds[cur];
        float4v sa[4] = {}, sb[4] = {};
        __builtin_amdgcn_s_setprio(1);
#pragma unroll
        for (int t4 = 0; t4 < 4; t4++) {
            int krow = t4 * 16 + lr;
            int sw = (krow & 7);
            short8v kfa = *(const short8v*)&Kf[krow * 64 + ((lg ^ sw) * 8)];
            short8v kfb = *(const short8v*)&Kf[krow * 64 + (((lg ^ 4) ^ sw) * 8)];
            sa[t4] = __builtin_amdgcn_mfma_f32_16x16x32_bf16(kfa, qf0a, sa[t4], 0, 0, 0);
            sa[t4] = __builtin_amdgcn_mfma_f32_16x16x32_bf16(kfb, qf1a, sa[t4], 0, 0, 0);
            if (dual) {
                sb[t4] = __builtin_amdgcn_mfma_f32_16x16x32_bf16(kfa, qf0b, sb[t4], 0, 0, 0);
                sb[t4] = __builtin_amdgcn_mfma_f32_16x16x32_bf16(kfb, qf1b, sb[t4], 0, 0, 0);
            }
        }
        __builtin_amdgcn_s_setprio(0);

        if (kv0 + 63 > q0a) {
#pragma unroll
            for (int t4 = 0; t4 < 4; t4++)
#pragma unroll
                for (int r = 0; r < 4; r++)
                    if (kv0 + t4 * 16 + 4 * lg + r > q0a + lr) sa[t4][r] = -3e38f;
        }
        if (dual && kv0 + 63 > q0b) {
#pragma unroll
            for (int t4 = 0; t4 < 4; t4++)
#pragma unroll
                for (int r = 0; r < 4; r++)
                    if (kv0 + t4 * 16 + 4 * lg + r > q0b + lr) sb[t4][r] = -3e38f;
        }

        short8v pa0, pa1, pb0, pb1;
        softmax_pack(sa, mra, lsa, oa, pa0, pa1);
        if (dual) softmax_pack(sb, mrb, lsb, ob, pb0, pb1);

        const short* Vf = (const short*)V_lds[cur];
        __builtin_amdgcn_s_setprio(1);
#pragma unroll
        for (int dt = 0; dt < 4; dt++) {
            int vrow = dt * 16 + lr;
            int sw = (vrow & 7);
            const short* Vr = Vf + vrow * 64;
            short4v a0 = *(const short4v*)&Vr[((g0    ) ^ sw) * 8 + hb];
            short4v a1 = *(const short4v*)&Vr[((g0 + 2) ^ sw) * 8 + hb];
            short4v b0 = *(const short4v*)&Vr[((g0 + 4) ^ sw) * 8 + hb];
            short4v b1 = *(const short4v*)&Vr[((g0 + 6) ^ sw) * 8 + hb];
            short8v vfa, vfb;
            vfa[0] = a0[0]; vfa[1] = a0[1]; vfa[2] = a0[2]; vfa[3] = a0[3];
            vfa[4] = a1[0]; vfa[5] = a1[1]; vfa[6] = a1[2]; vfa[7] = a1[3];
            vfb[0] = b0[0]; vfb[1] = b0[1]; vfb[2] = b0[2]; vfb[3] = b0[3];
            vfb[4] = b1[0]; vfb[5] = b1[1]; vfb[6] = b1[2]; vfb[7] = b1[3];
            oa[dt] = __builtin_amdgcn_mfma_f32_16x16x32_bf16(pa0, vfa, oa[dt], 0, 0, 0);
            oa[dt] = __builtin_amdgcn_mfma_f32_16x16x32_bf16(pa1, vfb, oa[dt], 0, 0, 0);
            if (dual) {
                ob[dt] = __builtin_amdgcn_mfma_f32_16x16x32_bf16(pb0, vfa, ob[dt], 0, 0, 0);
                ob[dt] = __builtin_amdgcn_mfma_f32_16x16x32_bf16(pb1, vfb, ob[dt], 0, 0, 0);
            }
        }
        __builtin_amdgcn_s_setprio(0);

        __syncthreads();
        cur ^= 1;
    }

    float la = lsa, lb = lsb;
    la += __shfl_xor(la, 16); la += __shfl_xor(la, 32);
    lb += __shfl_xor(lb, 16); lb += __shfl_xor(lb, 32);
    float inva_ = 1.0f / la, invb_ = 1.0f / lb;
    float inva[4], invb[4];
#pragma unroll
    for (int r = 0; r < 4; r++) {
        inva[r] = __shfl(inva_, lg * 4 + r);
        invb[r] = __shfl(invb_, lg * 4 + r);
    }
#pragma unroll
    for (int dt = 0; dt < 4; dt++)
#pragma unroll
        for (int r = 0; r < 4; r++) {
            int qa = q0a + lg * 4 + r;
            int qb = q0b + lg * 4 + r;
            Ob[((size_t)(b * 2048 + qa)) * 1024 + h * 64 + dt * 16 + lr] = f2bf(oa[dt][r] * inva[r]);
            Ob[((size_t)(b * 2048 + qb)) * 1024 + h * 64 + dt * 16 + lr] = f2bf(ob[dt][r] * invb[r]);
        }
}

extern "C" void kernel_launch(void* const* d_in, const int* in_sizes, int n_in,
                              void* d_out, int out_size, void* d_ws, size_t ws_size,
                              hipStream_t stream) {
    const float* x  = (const float*)d_in[0];
    const float* Wq = (const float*)d_in[1];
    const float* Wk = (const float*)d_in[2];
    const float* Wv = (const float*)d_in[3];
    const float* Wo = (const float*)d_in[4];
    float* out = (float*)d_out;

    char* ws = (char*)d_ws;
    short* xb  = (short*)(ws);                 // [4096][1024] bf16       8 MB
    short* Wtb = (short*)(ws + 8388608);       // 4 x [1024 n][1024 k]    8 MB
    short* Qb  = (short*)(ws + 16777216);      // [B,H,S,Dh] (pre-scaled) 8 MB
    short* Kb  = (short*)(ws + 25165824);      // [B,H,S,Dh]              8 MB
    short* Vtb = (short*)(ws + 33554432);      // [B,H,Dh,S]              8 MB
    short* Ob  = (short*)(ws + 41943040);      // [B,S,D] bf16            8 MB

    k_prep<<<8192, 256, 0, stream>>>(x, xb, Wq, Wk, Wv, Wo, Wtb);
    k_gemmQKV<<<dim3(32, 24), 256, 0, stream>>>(xb, Wtb, Qb, Kb, Vtb);
    k_attn<<<512, 256, 0, stream>>>(Qb, Kb, Vtb, Ob);
    k_gemmO<<<dim3(32, 8), 256, 0, stream>>>(Ob, Wtb + 3 * 1048576, out);
}

// Round 20
// 105.175 us; speedup vs baseline: 1.0685x; 1.0685x over previous
//
#include <hip/hip_runtime.h>

typedef __attribute__((ext_vector_type(4))) short short4v;
typedef __attribute__((ext_vector_type(8))) short short8v;
typedef __attribute__((ext_vector_type(4))) float float4v;
typedef __attribute__((ext_vector_type(4))) int int4v;

#define GLD_LDS16(gsrc, ldst)                                                             \
    __builtin_amdgcn_global_load_lds(                                                     \
        (const __attribute__((address_space(1))) void*)(gsrc),                            \
        (__attribute__((address_space(3))) void*)(ldst), 16, 0, 0)

__device__ __forceinline__ short f2bf(float f) {
    unsigned u = __builtin_bit_cast(unsigned, f);
    u += 0x7fffu + ((u >> 16) & 1u);
    return (short)(u >> 16);
}

// ---------------- fused prep: x cvt (blocks 0..4095) + W transpose (4096..8191) ----
__global__ void k_prep(const float* __restrict__ x, short* __restrict__ xb,
                       const float* __restrict__ W0, const float* __restrict__ W1,
                       const float* __restrict__ W2, const float* __restrict__ W3,
                       short* __restrict__ Wt) {
    __shared__ float tile[32][33];
    int bid = blockIdx.x;
    if (bid < 4096) {
        int i = bid * 256 + threadIdx.x;
        float4v v = ((const float4v*)x)[i];
        short4v o;
        o[0] = f2bf(v[0]); o[1] = f2bf(v[1]); o[2] = f2bf(v[2]); o[3] = f2bf(v[3]);
        ((short4v*)xb)[i] = o;
        return;
    }
    int L = bid - 4096;                  // 0..4095
    int z = L >> 10;                     // weight 0..3
    int xy = L & 1023;
    int bx = xy & 31, by = xy >> 5;
    const float* W = z == 0 ? W0 : z == 1 ? W1 : z == 2 ? W2 : W3;
    short* dst = Wt + (size_t)z * 1024 * 1024;
    int x0 = bx * 32, y0 = by * 32;
    int tx = threadIdx.x & 31, ty = threadIdx.x >> 5;   // 32 x 8
#pragma unroll
    for (int j = 0; j < 4; j++) {
        int r = ty + j * 8;
        tile[r][tx] = W[(size_t)(y0 + r) * 1024 + x0 + tx];
    }
    __syncthreads();
#pragma unroll
    for (int j = 0; j < 4; j++) {
        int r = ty + j * 8;
        dst[(size_t)(x0 + r) * 1024 + y0 + tx] = f2bf(tile[tx][r]);
    }
}

// ---------------- merged QKV GEMM: single dispatch, N=3072 (rows 0..3071 of Wtb) ----
__launch_bounds__(512, 4)
__global__ void k_gemmQKV(const short* __restrict__ A, const short* __restrict__ Wtb,
                          short* __restrict__ Qb, short* __restrict__ Kb,
                          short* __restrict__ Vtb) {
    __shared__ short As[2][128][64];
    __shared__ short Bs[2][128][64];
    int t = threadIdx.x;
    int l = t & 63, w = t >> 6;
    int wm = w >> 2, wn = w & 3;
    int lr = l & 15, lg = l >> 4;
    int m0 = blockIdx.x * 128;
    int nfull = blockIdx.y * 128;            // 0..2944 global weight-row base
    int which = nfull >> 10;                 // 0:Q 1:K 2:V (block-uniform)
    int nb = nfull & 1023;                   // within-weight column base

    int srow = l >> 3;
    int sg = (l & 7) ^ srow;
    const short* Ab0 = A + (size_t)(m0 + w * 8 + srow) * 1024 + sg * 8;
    const short* Ab1 = Ab0 + 64 * 1024;
    const short* Bb0 = Wtb + (size_t)(nfull + w * 8 + srow) * 1024 + sg * 8;
    const short* Bb1 = Bb0 + 64 * 1024;

    float4v acc[4][2] = {};

#define STAGE(bb, k0)                                   \
    do {                                                \
        GLD_LDS16(Ab0 + (k0), &As[bb][w * 8][0]);       \
        GLD_LDS16(Ab1 + (k0), &As[bb][64 + w * 8][0]);  \
        GLD_LDS16(Bb0 + (k0), &Bs[bb][w * 8][0]);       \
        GLD_LDS16(Bb1 + (k0), &Bs[bb][64 + w * 8][0]);  \
    } while (0)

    STAGE(0, 0);
    __syncthreads();
    int cur = 0;

    if (which == 2) {                        // block-uniform branch: V (swapped)
        for (int kt = 0; kt < 16; kt++) {
            if (kt + 1 < 16) STAGE(cur ^ 1, (kt + 1) * 64);
#pragma unroll
            for (int ks = 0; ks < 2; ks++) {
                short8v af[4], bfv[2];
                int hh = ks * 4 + lg;
                int sw = ((hh ^ (lr & 7)) * 8);
#pragma unroll
                for (int fm = 0; fm < 4; fm++)
                    af[fm] = *(const short8v*)&As[cur][wm * 64 + fm * 16 + lr][sw];
#pragma unroll
                for (int fn = 0; fn < 2; fn++)
                    bfv[fn] = *(const short8v*)&Bs[cur][wn * 32 + fn * 16 + lr][sw];
                __builtin_amdgcn_s_setprio(1);
#pragma unroll
                for (int fm = 0; fm < 4; fm++)
#pragma unroll
                    for (int fn = 0; fn < 2; fn++)
                        acc[fm][fn] = __builtin_amdgcn_mfma_f32_16x16x32_bf16(bfv[fn], af[fm], acc[fm][fn], 0, 0, 0);
                __builtin_amdgcn_s_setprio(0);
            }
            __syncthreads();
            cur ^= 1;
        }
    } else {
        for (int kt = 0; kt < 16; kt++) {
            if (kt + 1 < 16) STAGE(cur ^ 1, (kt + 1) * 64);
#pragma unroll
            for (int ks = 0; ks < 2; ks++) {
                short8v af[4], bfv[2];
                int hh = ks * 4 + lg;
                int sw = ((hh ^ (lr & 7)) * 8);
#pragma unroll
                for (int fm = 0; fm < 4; fm++)
                    af[fm] = *(const short8v*)&As[cur][wm * 64 + fm * 16 + lr][sw];
#pragma unroll
                for (int fn = 0; fn < 2; fn++)
                    bfv[fn] = *(const short8v*)&Bs[cur][wn * 32 + fn * 16 + lr][sw];
                __builtin_amdgcn_s_setprio(1);
#pragma unroll
                for (int fm = 0; fm < 4; fm++)
#pragma unroll
                    for (int fn = 0; fn < 2; fn++)
                        acc[fm][fn] = __builtin_amdgcn_mfma_f32_16x16x32_bf16(af[fm], bfv[fn], acc[fm][fn], 0, 0, 0);
                __builtin_amdgcn_s_setprio(0);
            }
            __syncthreads();
            cur ^= 1;
        }
    }
#undef STAGE

    if (which < 2) {
        short* out = (which == 0) ? Qb : Kb;
        float scale = (which == 0) ? 0.125f * 1.44269504088896f : 1.0f;
#pragma unroll
        for (int fm = 0; fm < 4; fm++)
#pragma unroll
            for (int fn = 0; fn < 2; fn++)
#pragma unroll
                for (int r = 0; r < 4; r++) {
                    int m = m0 + wm * 64 + fm * 16 + lg * 4 + r;
                    int n = nb + wn * 32 + fn * 16 + lr;
                    float v = acc[fm][fn][r] * scale;
                    int b = m >> 11, s = m & 2047, h = n >> 6, dh = n & 63;
                    out[(((size_t)(b * 16 + h)) * 2048 + s) * 64 + dh] = f2bf(v);
                }
    } else {
#pragma unroll
        for (int fm = 0; fm < 4; fm++)
#pragma unroll
            for (int fn = 0; fn < 2; fn++)
#pragma unroll
                for (int r = 0; r < 4; r++) {
                    int n = nb + wn * 32 + fn * 16 + lg * 4 + r;
                    int m = m0 + wm * 64 + fm * 16 + lr;
                    int b = m >> 11, s = m & 2047, h = n >> 6, dh = n & 63;
                    Vtb[(((size_t)(b * 16 + h)) * 64 + dh) * 2048 + s] = f2bf(acc[fm][fn][r]);
                }
    }
}

// ---------------- O-projection GEMM (fp32 out) ----------------
__launch_bounds__(512, 4)
__global__ void k_gemmO(const short* __restrict__ A, const short* __restrict__ Bt,
                        float* __restrict__ outF) {
    __shared__ short As[2][128][64];
    __shared__ short Bs[2][128][64];
    int t = threadIdx.x;
    int l = t & 63, w = t >> 6;
    int wm = w >> 2, wn = w & 3;
    int lr = l & 15, lg = l >> 4;
    int m0 = blockIdx.x * 128, n0 = blockIdx.y * 128;

    int srow = l >> 3;
    int sg = (l & 7) ^ srow;
    const short* Ab0 = A + (size_t)(m0 + w * 8 + srow) * 1024 + sg * 8;
    const short* Ab1 = Ab0 + 64 * 1024;
    const short* Bb0 = Bt + (size_t)(n0 + w * 8 + srow) * 1024 + sg * 8;
    const short* Bb1 = Bb0 + 64 * 1024;

    float4v acc[4][2] = {};

#define STAGE(bb, k0)                                   \
    do {                                                \
        GLD_LDS16(Ab0 + (k0), &As[bb][w * 8][0]);       \
        GLD_LDS16(Ab1 + (k0), &As[bb][64 + w * 8][0]);  \
        GLD_LDS16(Bb0 + (k0), &Bs[bb][w * 8][0]);       \
        GLD_LDS16(Bb1 + (k0), &Bs[bb][64 + w * 8][0]);  \
    } while (0)

    STAGE(0, 0);
    __syncthreads();
    int cur = 0;

    for (int kt = 0; kt < 16; kt++) {
        if (kt + 1 < 16) STAGE(cur ^ 1, (kt + 1) * 64);
#pragma unroll
        for (int ks = 0; ks < 2; ks++) {
            short8v af[4], bfv[2];
            int hh = ks * 4 + lg;
            int sw = ((hh ^ (lr & 7)) * 8);
#pragma unroll
            for (int fm = 0; fm < 4; fm++)
                af[fm] = *(const short8v*)&As[cur][wm * 64 + fm * 16 + lr][sw];
#pragma unroll
            for (int fn = 0; fn < 2; fn++)
                bfv[fn] = *(const short8v*)&Bs[cur][wn * 32 + fn * 16 + lr][sw];
            __builtin_amdgcn_s_setprio(1);
#pragma unroll
            for (int fm = 0; fm < 4; fm++)
#pragma unroll
                for (int fn = 0; fn < 2; fn++)
                    acc[fm][fn] = __builtin_amdgcn_mfma_f32_16x16x32_bf16(af[fm], bfv[fn], acc[fm][fn], 0, 0, 0);
            __builtin_amdgcn_s_setprio(0);
        }
        __syncthreads();
        cur ^= 1;
    }
#undef STAGE

#pragma unroll
    for (int fm = 0; fm < 4; fm++)
#pragma unroll
        for (int fn = 0; fn < 2; fn++)
#pragma unroll
            for (int r = 0; r < 4; r++) {
                int m = m0 + wm * 64 + fm * 16 + lg * 4 + r;
                int n = n0 + wn * 32 + fn * 16 + lr;
                outF[(size_t)m * 1024 + n] = acc[fm][fn][r];
            }
}

// ---------------- causal flash attention v16: in-register P (no LDS round-trip) ----
__launch_bounds__(256, 2)
__global__ void k_attn(const short* __restrict__ Qb, const short* __restrict__ Kb,
                       const short* __restrict__ Vtb, short* __restrict__ Ob) {
    __shared__ short K_lds[2][64][64];
    __shared__ short V_lds[2][64][64];
    int t = threadIdx.x;
    int l = t & 63, w = t >> 6;
    int lr = l & 15, lg = l >> 4;

    int L = blockIdx.x;                      // 0..511
    int bh = L & 31;                         // L%8 = bh%8 -> XCD affinity
    int g = L >> 5;                          // 0..15
    int p = (g < 8) ? g : 23 - g;            // heavy first; CU pair sums constant
    int nch = 32 - p;                        // staged chunks (covers hi tile)

    const short* Qp = Qb + (size_t)bh * 2048 * 64;
    const short* Kp = Kb + (size_t)bh * 2048 * 64;
    const short* Vp = Vtb + (size_t)bh * 64 * 2048;

    auto stage = [&](int bb, int kv0) {
#pragma unroll
        for (int i = 0; i < 2; i++) {
            int s = t + i * 256;
            int row = s >> 3, cg = s & 7;
            int cs = (cg ^ (row & 7)) * 8;
            GLD_LDS16(&Kp[(size_t)(kv0 + row) * 64 + cs], (short*)K_lds[bb] + (size_t)s * 8);
            GLD_LDS16(&Vp[(size_t)row * 2048 + kv0 + cs], (short*)V_lds[bb] + (size_t)s * 8);
        }
    };

    stage(0, 0);

    int q0a = (31 - p) * 64 + w * 16;        // sub-tile A rows (hi tile)
    int q0b = p * 64 + w * 16;               // sub-tile B rows (lo tile)
    short8v qf0a = *(const short8v*)&Qp[(size_t)(q0a + lr) * 64 + lg * 8];
    short8v qf1a = *(const short8v*)&Qp[(size_t)(q0a + lr) * 64 + 32 + lg * 8];
    short8v qf0b = *(const short8v*)&Qp[(size_t)(q0b + lr) * 64 + lg * 8];
    short8v qf1b = *(const short8v*)&Qp[(size_t)(q0b + lr) * 64 + 32 + lg * 8];

    float4v oa[4] = {}, ob[4] = {};
    float mra = -3e38f, mrb = -3e38f;
    float lsa = 0.f, lsb = 0.f;
    int cur = 0;
    int b = bh >> 4, h = bh & 15;
    int g0 = lg >> 1;
    int hb = (lg & 1) * 4;

    auto softmax_pack = [&](float4v (&s)[4], float& mr, float& ls, float4v (&o)[4],
                            short8v& pa0, short8v& pa1) {
        float mx = -3e38f;
#pragma unroll
        for (int t4 = 0; t4 < 4; t4++)
#pragma unroll
            for (int r = 0; r < 4; r++) mx = fmaxf(mx, s[t4][r]);

        if (!__all(mx - mr <= 8.f)) {
            float m_ = fmaxf(mx, __shfl_xor(mx, 16));
            m_ = fmaxf(m_, __shfl_xor(m_, 32));
            float mnew = fmaxf(mr, m_);
            float sc = __builtin_amdgcn_exp2f(mr - mnew);
            mr = mnew;
            ls *= sc;
#pragma unroll
            for (int r = 0; r < 4; r++) {
                float scq = __shfl(sc, lg * 4 + r);
                o[0][r] *= scq; o[1][r] *= scq; o[2][r] *= scq; o[3][r] *= scq;
            }
        }
        unsigned d[8];
#pragma unroll
        for (int t4 = 0; t4 < 4; t4++) {
            float e0 = __builtin_amdgcn_exp2f(s[t4][0] - mr);
            float e1 = __builtin_amdgcn_exp2f(s[t4][1] - mr);
            float e2 = __builtin_amdgcn_exp2f(s[t4][2] - mr);
            float e3 = __builtin_amdgcn_exp2f(s[t4][3] - mr);
            ls += (e0 + e1) + (e2 + e3);
            asm("v_cvt_pk_bf16_f32 %0, %1, %2" : "=v"(d[2 * t4])     : "v"(e0), "v"(e1));
            asm("v_cvt_pk_bf16_f32 %0, %1, %2" : "=v"(d[2 * t4 + 1]) : "v"(e2), "v"(e3));
        }
        pa0 = __builtin_bit_cast(short8v, int4v{(int)d[0], (int)d[1], (int)d[2], (int)d[3]});
        pa1 = __builtin_bit_cast(short8v, int4v{(int)d[4], (int)d[5], (int)d[6], (int)d[7]});
    };

    __syncthreads();

    for (int ci = 0; ci < nch; ci++) {
        int kv0 = ci * 64;
        bool dual = (ci <= p);

        if (ci + 1 < nch) stage(cur ^ 1, (ci + 1) * 64);

        const short* Kf = (const short*)K_lds[cur];
        float4v sa[4] = {}, sb[4] = {};
        __builtin_amdgcn_s_setprio(1);
#pragma unroll
        for (int t4 = 0; t4 < 4; t4++) {
            int krow = t4 * 16 + lr;
            int sw = (krow & 7);
            short8v kfa = *(const short8v*)&Kf[krow * 64 + ((lg ^ sw) * 8)];
            short8v kfb = *(const short8v*)&Kf[krow * 64 + (((lg ^ 4) ^ sw) * 8)];
            sa[t4] = __builtin_amdgcn_mfma_f32_16x16x32_bf16(kfa, qf0a, sa[t4], 0, 0, 0);
            sa[t4] = __builtin_amdgcn_mfma_f32_16x16x32_bf16(kfb, qf1a, sa[t4], 0, 0, 0);
            if (dual) {
                sb[t4] = __builtin_amdgcn_mfma_f32_16x16x32_bf16(kfa, qf0b, sb[t4], 0, 0, 0);
                sb[t4] = __builtin_amdgcn_mfma_f32_16x16x32_bf16(kfb, qf1b, sb[t4], 0, 0, 0);
            }
        }
        __builtin_amdgcn_s_setprio(0);

        if (kv0 + 63 > q0a) {
#pragma unroll
            for (int t4 = 0; t4 < 4; t4++)
#pragma unroll
                for (int r = 0; r < 4; r++)
                    if (kv0 + t4 * 16 + 4 * lg + r > q0a + lr) sa[t4][r] = -3e38f;
        }
        if (dual && kv0 + 63 > q0b) {
#pragma unroll
            for (int t4 = 0; t4 < 4; t4++)
#pragma unroll
                for (int r = 0; r < 4; r++)
                    if (kv0 + t4 * 16 + 4 * lg + r > q0b + lr) sb[t4][r] = -3e38f;
        }

        short8v pa0, pa1, pb0, pb1;
        softmax_pack(sa, mra, lsa, oa, pa0, pa1);
        if (dual) softmax_pack(sb, mrb, lsb, ob, pb0, pb1);

        const short* Vf = (const short*)V_lds[cur];
        __builtin_amdgcn_s_setprio(1);
#pragma unroll
        for (int dt = 0; dt < 4; dt++) {
            int vrow = dt * 16 + lr;
            int sw = (vrow & 7);
            const short* Vr = Vf + vrow * 64;
            short4v a0 = *(const short4v*)&Vr[((g0    ) ^ sw) * 8 + hb];
            short4v a1 = *(const short4v*)&Vr[((g0 + 2) ^ sw) * 8 + hb];
            short4v b0 = *(const short4v*)&Vr[((g0 + 4) ^ sw) * 8 + hb];
            short4v b1 = *(const short4v*)&Vr[((g0 + 6) ^ sw) * 8 + hb];
            short8v vfa, vfb;
            vfa[0] = a0[0]; vfa[1] = a0[1]; vfa[2] = a0[2]; vfa[3] = a0[3];
            vfa[4] = a1[0]; vfa[5] = a1[1]; vfa[6] = a1[2]; vfa[7] = a1[3];
            vfb[0] = b0[0]; vfb[1] = b0[1]; vfb[2] = b0[2]; vfb[3] = b0[3];
            vfb[4] = b1[0]; vfb[5] = b1[1]; vfb[6] = b1[2]; vfb[7] = b1[3];
            oa[dt] = __builtin_amdgcn_mfma_f32_16x16x32_bf16(pa0, vfa, oa[dt], 0, 0, 0);
            oa[dt] = __builtin_amdgcn_mfma_f32_16x16x32_bf16(pa1, vfb, oa[dt], 0, 0, 0);
            if (dual) {
                ob[dt] = __builtin_amdgcn_mfma_f32_16x16x32_bf16(pb0, vfa, ob[dt], 0, 0, 0);
                ob[dt] = __builtin_amdgcn_mfma_f32_16x16x32_bf16(pb1, vfb, ob[dt], 0, 0, 0);
            }
        }
        __builtin_amdgcn_s_setprio(0);

        __syncthreads();
        cur ^= 1;
    }

    float la = lsa, lb = lsb;
    la += __shfl_xor(la, 16); la += __shfl_xor(la, 32);
    lb += __shfl_xor(lb, 16); lb += __shfl_xor(lb, 32);
    float inva_ = 1.0f / la, invb_ = 1.0f / lb;
    float inva[4], invb[4];
#pragma unroll
    for (int r = 0; r < 4; r++) {
        inva[r] = __shfl(inva_, lg * 4 + r);
        invb[r] = __shfl(invb_, lg * 4 + r);
    }
#pragma unroll
    for (int dt = 0; dt < 4; dt++)
#pragma unroll
        for (int r = 0; r < 4; r++) {
            int qa = q0a + lg * 4 + r;
            int qb = q0b + lg * 4 + r;
            Ob[((size_t)(b * 2048 + qa)) * 1024 + h * 64 + dt * 16 + lr] = f2bf(oa[dt][r] * inva[r]);
            Ob[((size_t)(b * 2048 + qb)) * 1024 + h * 64 + dt * 16 + lr] = f2bf(ob[dt][r] * invb[r]);
        }
}

extern "C" void kernel_launch(void* const* d_in, const int* in_sizes, int n_in,
                              void* d_out, int out_size, void* d_ws, size_t ws_size,
                              hipStream_t stream) {
    const float* x  = (const float*)d_in[0];
    const float* Wq = (const float*)d_in[1];
    const float* Wk = (const float*)d_in[2];
    const float* Wv = (const float*)d_in[3];
    const float* Wo = (const float*)d_in[4];
    float* out = (float*)d_out;

    char* ws = (char*)d_ws;
    short* xb  = (short*)(ws);                 // [4096][1024] bf16       8 MB
    short* Wtb = (short*)(ws + 8388608);       // 4 x [1024 n][1024 k]    8 MB
    short* Qb  = (short*)(ws + 16777216);      // [B,H,S,Dh] (pre-scaled) 8 MB
    short* Kb  = (short*)(ws + 25165824);      // [B,H,S,Dh]              8 MB
    short* Vtb = (short*)(ws + 33554432);      // [B,H,Dh,S]              8 MB
    short* Ob  = (short*)(ws + 41943040);      // [B,S,D] bf16            8 MB

    k_prep<<<8192, 256, 0, stream>>>(x, xb, Wq, Wk, Wv, Wo, Wtb);
    k_gemmQKV<<<dim3(32, 24), 512, 0, stream>>>(xb, Wtb, Qb, Kb, Vtb);
    k_attn<<<512, 256, 0, stream>>>(Qb, Kb, Vtb, Ob);
    k_gemmO<<<dim3(32, 8), 512, 0, stream>>>(Ob, Wtb + 3 * 1048576, out);
}